// Round 13
// baseline (583.191 us; speedup 1.0000x reference)
//
#include <hip/hip_runtime.h>

typedef unsigned short u16;
typedef unsigned int u32;
typedef __attribute__((ext_vector_type(8))) short bf16x8;
typedef __attribute__((ext_vector_type(4))) float f32x4;

#define NTOK 65536
#define DM 512
#define DI 1024

__device__ __forceinline__ float bf2f(u16 u){ u32 x=((u32)u)<<16; float f; __builtin_memcpy(&f,&x,4); return f; }
__device__ __forceinline__ u16 f2bf(float f){ u32 u; __builtin_memcpy(&u,&f,4); u += 0x7fffu + ((u>>16)&1u); return (u16)(u>>16); }
__device__ __forceinline__ float siluf(float x){ return x/(1.f+__expf(-x)); }
// fast softplus: log(1+e^x) via HW exp/log; guard matches reference large-x behavior
__device__ __forceinline__ float softplus_fast(float x){
  float l = __logf(1.f + __expf(x));
  return (x > 20.f) ? x : l;
}

__device__ __forceinline__ void gload_lds16(const void* g, void* l){
  __builtin_amdgcn_global_load_lds((const __attribute__((address_space(1))) u32*)g,
                                   (__attribute__((address_space(3))) u32*)l, 16, 0, 0);
}

__global__ void k_sentinel(float* out){ out[0] = 1.2345e6f; }

__global__ void k_cast_bf16(const float* __restrict__ in, u16* __restrict__ out, int n){
  int i = (blockIdx.x*256 + threadIdx.x)*4;
  if (i >= n) return;
  float4 v = *(const float4*)(in + i);
  ushort4 o; o.x=f2bf(v.x); o.y=f2bf(v.y); o.z=f2bf(v.z); o.w=f2bf(v.w);
  *(ushort4*)(out + i) = o;
}

// one launch for the three small weight casts: ipw (1M), xpw (64K), dpw (32K)
__global__ void k_cast_weights(const float* __restrict__ ipw_f, const float* __restrict__ xpw_f,
                               const float* __restrict__ dpw_f,
                               u16* __restrict__ ipw, u16* __restrict__ xpw, u16* __restrict__ dpw){
  int b = blockIdx.x;
  const float* src; u16* dst; int base;
  if (b < 1024){ src=ipw_f; dst=ipw; base = b*1024; }
  else if (b < 1088){ src=xpw_f; dst=xpw; base = (b-1024)*1024; }
  else { src=dpw_f; dst=dpw; base = (b-1088)*1024; }
  int i = base + threadIdx.x*4;
  float4 v = *(const float4*)(src + i);
  ushort4 o; o.x=f2bf(v.x); o.y=f2bf(v.y); o.z=f2bf(v.z); o.w=f2bf(v.w);
  *(ushort4*)(dst + i) = o;
}

// W_a[i][j] = sum_c fc_w[i][c] * out_proj_w[c][j], padded to 64 rows (zeros), bf16
__global__ void k_make_wa(const float* __restrict__ fcw, const float* __restrict__ opw,
                          u16* __restrict__ wa){
  int j = blockIdx.x*256 + threadIdx.x;   // 0..1023
  int i = blockIdx.y;                     // 0..63
  float s = 0.f;
  if (i < 36){
    const float* fr = fcw + i*DM;
    #pragma unroll 8
    for (int k=0;k<DM;++k) s += fr[k]*opw[(size_t)k*DI + j];
  }
  wa[(size_t)i*DI + j] = f2bf(s);
}

// xz = f @ in_proj^T. A-frags DIRECT global->VGPR (L1/L2-served, halves LDS traffic);
// B in LDS dbuf (R4 staging/swizzle). XCD-bijective grid. grid (16,512).
__global__ __launch_bounds__(256) void k_gemm_xz(
  const u16* __restrict__ A, const u16* __restrict__ B,
  const float* __restrict__ convw, const float* __restrict__ convb,
  u16* __restrict__ xp, u16* __restrict__ zs)
{
  __shared__ u16 smem[20480];             // 40 KB: B dbuf 2x8192 u16; epilogue [128][160]
  const int tid=threadIdx.x, wv=tid>>6, ln=tid&63;
  const int l15=ln&15, l4=ln>>4, h=l15&7;
  const int l = blockIdx.y*16 + blockIdx.x;
  const int xcd = l & 7, q = l >> 3;
  const int cb = q & 15;                  // col-block 0..15
  const int g  = (q >> 4)*8 + xcd;        // row-group 0..511 (bijective)
  const int c0g = cb*128, r0 = g*128;
  const int wm=wv>>1, wn=wv&1;
  const int sr=ln>>3, scs=((ln&7)^sr)*8;       // pre-swizzled global col chunk (B staging)
  const int chk0=(l4^h)*8, chk1=((l4+4)^h)*8;  // swizzled read chunk offsets (B reads)
  const int rB=(wn*64+l15)*64;
  f32x4 acc[4][4]={};

  auto STAGE_B=[&](int buf, int k0){
    u16* Bd = smem + buf*8192;
    #pragma unroll
    for (int it=0;it<4;++it){
      int c=wv*4+it;
      gload_lds16(B + (size_t)(c0g + c*8 + sr)*DM + k0 + scs, Bd + c*512);
    }
  };

  // A-frag base pointers: row = r0 + wm*64 + m*16 + l15, k = t*64 + kk*32 + l4*8
  const u16* Ap[4];
  #pragma unroll
  for (int m=0;m<4;++m) Ap[m] = A + (size_t)(r0 + wm*64 + m*16 + l15)*DM + l4*8;

  bf16x8 afc[4][2], afn[4][2];
  #pragma unroll
  for (int m=0;m<4;++m){
    afc[m][0] = *(const bf16x8*)(Ap[m]);
    afc[m][1] = *(const bf16x8*)(Ap[m] + 32);
  }
  STAGE_B(0, 0);
  __syncthreads();
  __builtin_amdgcn_sched_barrier(0);
  int cur = 0;
  #pragma clang loop unroll(disable)
  for (int t=0;t<8;++t){
    if (t < 7){
      STAGE_B(cur^1, (t+1)*64);
      #pragma unroll
      for (int m=0;m<4;++m){
        afn[m][0] = *(const bf16x8*)(Ap[m] + (t+1)*64);
        afn[m][1] = *(const bf16x8*)(Ap[m] + (t+1)*64 + 32);
      }
    }
    const u16* Bc = smem + cur*8192;
    #pragma unroll
    for (int kk=0;kk<2;++kk){
      const int ch = kk ? chk1 : chk0;
      bf16x8 bfr[4];
      #pragma unroll
      for (int n=0;n<4;++n) bfr[n]=*(const bf16x8*)(Bc + rB + n*1024 + ch);
      #pragma unroll
      for (int m=0;m<4;++m)
        #pragma unroll
        for (int n=0;n<4;++n)
          acc[m][n]=__builtin_amdgcn_mfma_f32_16x16x32_bf16(afc[m][kk],bfr[n],acc[m][n],0,0,0);
    }
    __syncthreads();
    __builtin_amdgcn_sched_barrier(0);
    #pragma unroll
    for (int m=0;m<4;++m){ afc[m][0]=afn[m][0]; afc[m][1]=afn[m][1]; }
    cur ^= 1;
  }

  // Epilogue: activation -> LDS tile [128][160 u16] (320B stride) -> coalesced stores
  const bool isx = (c0g < DI);
  const int cc0 = isx ? c0g : c0g - DI;
  u16* ep = smem;
  #pragma unroll
  for (int n=0;n<4;++n){
    int tcol = wn*64 + n*16 + l15;
    int gcol = c0g + tcol;
    float cw = isx ? convw[gcol*4+3] : 0.f;
    float cb2= isx ? convb[gcol]     : 0.f;
    #pragma unroll
    for (int m=0;m<4;++m){
      int trow = wm*64 + m*16 + l4*4;
      #pragma unroll
      for (int r=0;r<4;++r){
        float v = acc[m][n][r];
        float o = isx ? siluf(v*cw + cb2) : siluf(v);
        ep[(trow+r)*160 + tcol] = f2bf(o);
      }
    }
  }
  __syncthreads();
  int rrow = tid>>1, half = tid&1;
  const u16* srcp = ep + rrow*160 + half*64;
  u16* dst = (isx ? xp : zs) + (size_t)(r0+rrow)*DI + cc0 + half*64;
  #pragma unroll
  for (int j=0;j<8;++j)
    *(int4*)(dst + j*8) = *(const int4*)(srcp + j*8);
}

// MERGED TAIL: phase 1 = x_dbl GEMM (xp @ xpw^T, K=1024) -> dtb/bc in LDS;
// phase 2 = delta GEMM + w=softplus*bc+D + y=w*xp*zs (LDS) + out GEMM vs wa + fcb.
// grid 512 x 256 thr (4 waves). 59.9 KB LDS -> 2 blocks/CU. All plain __syncthreads.
__global__ __launch_bounds__(256) void k_tail(
  const u16* __restrict__ xp, const u16* __restrict__ xpw,
  const u16* __restrict__ dpw,
  const float* __restrict__ dpb, const float* __restrict__ Dv,
  const u16* __restrict__ zs, const u16* __restrict__ wa,
  const float* __restrict__ fcb, float* __restrict__ out)
{
  __shared__ u16 smem[29952];            // 59.9 KB
  u16*   As  = smem;                     // [0,4096): dt tile 128x32 bf16 (persistent)
  float* bcs = (float*)(smem + 4096);    // [4096,4352): bc[128] (persistent)
  u16*   S   = smem + 4352;              // 25600 u16 scratch
  const int tid=threadIdx.x, wv=tid>>6, ln=tid&63;
  const int l15=ln&15, l4=ln>>4, h=l15&7;
  const int r0=blockIdx.x*128;
  const int wm=wv>>1, wn=wv&1;
  const int sr=ln>>3, scs=((ln&7)^sr)*8;
  const int chk0=(l4^h)*8, chk1=((l4+4)^h)*8;
  const int rA=(wm*64+l15)*64, rB=(wn*32+l15)*64;
  const int sr2=ln>>2, sc2=(ln&3)*8;     // phase-2 staging map (16 rows/chunk)

  // ---------------- phase 1: x_dbl = xp @ xpw^T ----------------
  {
    f32x4 acc[4][2]={};
    auto STAGE=[&](int buf, int k0){
      u16* Ad = S + buf*8192;
      u16* Bd = S + 16384 + buf*4096;
      #pragma unroll
      for (int it=0;it<4;++it){
        int c=wv*4+it;
        gload_lds16(xp + (size_t)(r0 + c*8 + sr)*DI + k0 + scs, Ad + c*512);
      }
      #pragma unroll
      for (int it=0;it<2;++it){
        int c=wv*2+it;
        gload_lds16(xpw + (size_t)(c*8 + sr)*DI + k0 + scs, Bd + c*512);
      }
    };
    STAGE(0, 0);
    __syncthreads();
    __builtin_amdgcn_sched_barrier(0);
    int cur = 0;
    #pragma clang loop unroll(disable)
    for (int t=0;t<16;++t){
      if (t < 15) STAGE(cur^1, (t+1)*64);
      const u16* Ac = S + cur*8192;
      const u16* Bc = S + 16384 + cur*4096;
      #pragma unroll
      for (int kk=0;kk<2;++kk){
        const int ch = kk ? chk1 : chk0;
        bf16x8 af[4], bfr[2];
        #pragma unroll
        for (int m=0;m<4;++m) af[m]=*(const bf16x8*)(Ac + rA + m*1024 + ch);
        #pragma unroll
        for (int n=0;n<2;++n) bfr[n]=*(const bf16x8*)(Bc + rB + n*1024 + ch);
        #pragma unroll
        for (int m=0;m<4;++m)
          #pragma unroll
          for (int n=0;n<2;++n)
            acc[m][n]=__builtin_amdgcn_mfma_f32_16x16x32_bf16(af[m],bfr[n],acc[m][n],0,0,0);
      }
      __syncthreads();
      __builtin_amdgcn_sched_barrier(0);
      cur ^= 1;
    }
    // restage fp32 x_dbl tile [128][68] over dead SA/SB
    float* W = (float*)S;
    #pragma unroll
    for (int n=0;n<2;++n){
      int j = wn*32 + n*16 + l15;
      #pragma unroll
      for (int m=0;m<4;++m){
        int trow = wm*64 + m*16 + l4*4;
        #pragma unroll
        for (int r=0;r<4;++r)
          W[(trow+r)*68 + j] = acc[m][n][r];
      }
    }
    __syncthreads();
    // emit As (bf16 dt tile) + bcs; stage Bs[0] (disjoint region S+17408..) in parallel
    const int row = tid>>1, half = tid&1;
    const float* wr = W + row*68;
    if (half==0){
      #pragma unroll
      for (int qv=0;qv<4;++qv){
        bf16x8 o;
        #pragma unroll
        for (int e=0;e<8;++e) o[e] = (short)f2bf(wr[qv*8+e]);
        *(bf16x8*)(As + row*32 + qv*8) = o;
      }
    } else {
      float s=0.f;
      #pragma unroll
      for (int e=0;e<16;++e) s += wr[32+e]*wr[48+e];
      bcs[row] = s;
    }
    {
      u16* Bs0 = S + 17408;
      #pragma unroll
      for (int it=0;it<2;++it){
        int c=wv*2+it;
        gload_lds16(dpw + (size_t)(c*16 + sr2)*32 + sc2, Bs0 + c*512);
      }
    }
    __syncthreads();   // drains gload (vmcnt) + orders As/bcs/W
  }

  // ---------------- phase 2: delta + y + out GEMM ----------------
  u16* Y   = S;                  // overwrites dead W
  u16* BsB = S + 17408;          // 2 x 4096 u16
  bf16x8 af[4];                  // persistent dt A-frags
  #pragma unroll
  for (int m=0;m<4;++m) af[m]=*(const bf16x8*)(As + (wm*64+m*16+l15)*32 + l4*8);

  f32x4 oacc[2][4]={};
  const int yrow = tid>>1, yhalf = tid&1;
  int cur = 0;

  #pragma clang loop unroll(disable)
  for (int ch=0; ch<8; ++ch){
    // GEMM1: delta chunk (128 x 128), K=32
    f32x4 dacc[4][4]={};
    bf16x8 bfr[4];
    #pragma unroll
    for (int n=0;n<4;++n) bfr[n]=*(const bf16x8*)(BsB + cur*4096 + (wn*64+n*16+l15)*32 + l4*8);
    #pragma unroll
    for (int m=0;m<4;++m)
      #pragma unroll
      for (int n=0;n<4;++n)
        dacc[m][n]=__builtin_amdgcn_mfma_f32_16x16x32_bf16(af[m],bfr[n],dacc[m][n],0,0,0);
    if (ch<7){
      #pragma unroll
      for (int it=0;it<2;++it){
        int c=wv*2+it;
        gload_lds16(dpw + (size_t)((ch+1)*128 + c*16 + sr2)*32 + sc2, BsB + (cur^1)*4096 + c*512);
      }
    }
    // w-pass: w = softplus(dacc+dpb)*bc+D -> Y (bf16, frag-scatter)
    #pragma unroll
    for (int n=0;n<4;++n){
      int tcol = wn*64 + n*16 + l15;           // 0..127
      int j = ch*128 + tcol;
      float dpbj = dpb[j], Dj = Dv[j];
      #pragma unroll
      for (int m=0;m<4;++m){
        int trow = wm*64 + m*16 + l4*4;
        #pragma unroll
        for (int r=0;r<4;++r){
          float delta = softplus_fast(dacc[m][n][r] + dpbj);
          float w = delta*bcs[trow + r] + Dj;
          Y[(trow+r)*136 + tcol] = f2bf(w);
        }
      }
    }
    __syncthreads();
    // y-finish: y = w * xp * zs, vectorized, back into Y
    {
      u16* wp = Y + yrow*136 + yhalf*64;
      const size_t gbase = (size_t)(r0 + yrow)*DI + ch*128 + yhalf*64;
      const u16* xpp = xp + gbase;
      const u16* zp  = zs + gbase;
      #pragma unroll
      for (int qq=0;qq<8;++qq){
        bf16x8 wv8 = *(const bf16x8*)(wp + qq*8);
        bf16x8 xv  = *(const bf16x8*)(xpp + qq*8);
        bf16x8 zv  = *(const bf16x8*)(zp + qq*8);
        bf16x8 ov;
        #pragma unroll
        for (int e=0;e<8;++e){
          float y = bf2f((u16)wv8[e]) * bf2f((u16)xv[e]) * bf2f((u16)zv[e]);
          ov[e] = (short)f2bf(y);
        }
        *(bf16x8*)(wp + qq*8) = ov;
      }
    }
    __syncthreads();
    // GEMM2: out += y_chunk (128x128) @ wa_chunk^T (64x128)
    #pragma unroll
    for (int kk=0;kk<4;++kk){
      bf16x8 af2[2], bf2r[4];
      #pragma unroll
      for (int m=0;m<2;++m)
        af2[m]=*(const bf16x8*)(Y + (wv*32 + m*16 + l15)*136 + kk*32 + l4*8);
      #pragma unroll
      for (int n=0;n<4;++n)
        bf2r[n]=*(const bf16x8*)(wa + (size_t)(n*16 + l15)*DI + ch*128 + kk*32 + l4*8);
      #pragma unroll
      for (int m=0;m<2;++m)
        #pragma unroll
        for (int n=0;n<4;++n)
          oacc[m][n]=__builtin_amdgcn_mfma_f32_16x16x32_bf16(af2[m],bf2r[n],oacc[m][n],0,0,0);
    }
    __syncthreads();   // Y reads done before next w-pass; Bs prefetch landed
    __builtin_amdgcn_sched_barrier(0);
    cur ^= 1;
  }

  // epilogue: out[t*36+j] = oacc + fcb[j], j<36
  #pragma unroll
  for (int n=0;n<4;++n){
    int j = n*16 + l15;
    if (j < 36){
      float fj = fcb[j];
      #pragma unroll
      for (int m=0;m<2;++m){
        #pragma unroll
        for (int r=0;r<4;++r){
          int t = r0 + wv*32 + m*16 + l4*4 + r;
          out[(size_t)t*36 + j] = oacc[m][n][r] + fj;
        }
      }
    }
  }
}

extern "C" void kernel_launch(void* const* d_in, const int* in_sizes, int n_in,
                              void* d_out, int out_size, void* d_ws, size_t ws_size,
                              hipStream_t stream){
  const float* f      = (const float*)d_in[0];
  const float* inpw   = (const float*)d_in[1];
  const float* convw  = (const float*)d_in[2];
  const float* convb  = (const float*)d_in[3];
  const float* xprojw = (const float*)d_in[4];
  const float* dtpw   = (const float*)d_in[5];
  const float* dtpb   = (const float*)d_in[6];
  const float* Dv     = (const float*)d_in[8];
  const float* opw    = (const float*)d_in[9];
  const float* fcw    = (const float*)d_in[10];
  const float* fcb    = (const float*)d_in[11];
  float* out = (float*)d_out;

  char* ws = (char*)d_ws;
  size_t off = 0;
  auto alloc = [&](size_t sz)->void*{ void* p = ws + off; off += (sz + 255) & ~(size_t)255; return p; };
  u16*   fbf = (u16*)  alloc((size_t)NTOK*DM*2);
  u16*   xp  = (u16*)  alloc((size_t)NTOK*DI*2);
  u16*   zy  = (u16*)  alloc((size_t)NTOK*DI*2);
  u16*   ipw = (u16*)  alloc((size_t)2048*512*2);
  u16*   xpw = (u16*)  alloc((size_t)64*1024*2);
  u16*   dpw = (u16*)  alloc((size_t)1024*32*2);
  u16*   wa  = (u16*)  alloc((size_t)64*1024*2);
  if (off > ws_size){ k_sentinel<<<1,1,0,stream>>>(out); return; }

  k_cast_bf16<<<dim3((NTOK*DM/4)/256),256,0,stream>>>(f, fbf, NTOK*DM);
  k_cast_weights<<<dim3(1120),256,0,stream>>>(inpw, xprojw, dtpw, ipw, xpw, dpw);
  k_make_wa<<<dim3(4,64),256,0,stream>>>(fcw, opw, wa);

  k_gemm_xz<<<dim3(16,512),256,0,stream>>>(fbf, ipw, convw, convb, xp, zy);
  k_tail<<<dim3(512),256,0,stream>>>(xp, xpw, dpw, dtpb, Dv, zy, wa, fcb, out);
}

// Round 15
// 561.001 us; speedup vs baseline: 1.0396x; 1.0396x over previous
//
#include <hip/hip_runtime.h>

typedef unsigned short u16;
typedef unsigned int u32;
typedef __attribute__((ext_vector_type(8))) short bf16x8;
typedef __attribute__((ext_vector_type(4))) float f32x4;

#define NTOK 65536
#define DM 512
#define DI 1024

__device__ __forceinline__ float bf2f(u16 u){ u32 x=((u32)u)<<16; float f; __builtin_memcpy(&f,&x,4); return f; }
__device__ __forceinline__ u16 f2bf(float f){ u32 u; __builtin_memcpy(&u,&f,4); u += 0x7fffu + ((u>>16)&1u); return (u16)(u>>16); }
__device__ __forceinline__ float siluf(float x){ return x/(1.f+__expf(-x)); }
__device__ __forceinline__ float softplus_fast(float x){
  float l = __logf(1.f + __expf(x));
  return (x > 20.f) ? x : l;
}

__device__ __forceinline__ void gload_lds16(const void* g, void* l){
  __builtin_amdgcn_global_load_lds((const __attribute__((address_space(1))) u32*)g,
                                   (__attribute__((address_space(3))) u32*)l, 16, 0, 0);
}

__global__ void k_sentinel(float* out){ out[0] = 1.2345e6f; }

__global__ void k_cast_bf16(const float* __restrict__ in, u16* __restrict__ out, int n){
  int i = (blockIdx.x*256 + threadIdx.x)*4;
  if (i >= n) return;
  float4 v = *(const float4*)(in + i);
  ushort4 o; o.x=f2bf(v.x); o.y=f2bf(v.y); o.z=f2bf(v.z); o.w=f2bf(v.w);
  *(ushort4*)(out + i) = o;
}

__global__ void k_cast_weights(const float* __restrict__ ipw_f, const float* __restrict__ xpw_f,
                               const float* __restrict__ dpw_f,
                               u16* __restrict__ ipw, u16* __restrict__ xpw, u16* __restrict__ dpw){
  int b = blockIdx.x;
  const float* src; u16* dst; int base;
  if (b < 1024){ src=ipw_f; dst=ipw; base = b*1024; }
  else if (b < 1088){ src=xpw_f; dst=xpw; base = (b-1024)*1024; }
  else { src=dpw_f; dst=dpw; base = (b-1088)*1024; }
  int i = base + threadIdx.x*4;
  float4 v = *(const float4*)(src + i);
  ushort4 o; o.x=f2bf(v.x); o.y=f2bf(v.y); o.z=f2bf(v.z); o.w=f2bf(v.w);
  *(ushort4*)(dst + i) = o;
}

// W_a[i][j] = sum_c fc_w[i][c] * out_proj_w[c][j], padded to 64 rows (zeros), bf16
__global__ void k_make_wa(const float* __restrict__ fcw, const float* __restrict__ opw,
                          u16* __restrict__ wa){
  int j = blockIdx.x*256 + threadIdx.x;
  int i = blockIdx.y;
  float s = 0.f;
  if (i < 36){
    const float* fr = fcw + i*DM;
    #pragma unroll 8
    for (int k=0;k<DM;++k) s += fr[k]*opw[(size_t)k*DI + j];
  }
  wa[(size_t)i*DI + j] = f2bf(s);
}

// xz = f @ in_proj^T. m201 8-phase template: 256x256 tile, BK=64, 512 thr (2Mx4N waves,
// wave-tile 128x64), 128KB LDS = 2dbuf x (A 2half + B 2half), chunk-transposed layout,
// counted vmcnt(4) at K-tile boundaries only, setprio around MFMA, XCD-bijective grid.
// grid 2048: xcd=l&7, q=l>>3, cb=q&7, g=(q>>3)*8+xcd.
__global__ __launch_bounds__(512,1) void k_gemm_xz(
  const u16* __restrict__ A, const u16* __restrict__ B,
  const float* __restrict__ convw, const float* __restrict__ convb,
  u16* __restrict__ xp, u16* __restrict__ zs)
{
  __shared__ u16 smem[65536];   // 128 KB: dbuf d at d*32768: A halves at +0,+8192; B at +16384,+24576
  const int tid=threadIdx.x, wv=tid>>6, ln=tid&63;
  const int l15=ln&15, l4=ln>>4;
  const int l=blockIdx.x, xcd=l&7, q0=l>>3;
  const int cb=q0&7, g=(q0>>3)*8+xcd;     // g 0..255, cb 0..7 (bijective)
  const size_t r0=(size_t)g*256; const int c0=cb*256;
  const int wm=wv>>2, wn=wv&3;            // 2M x 4N waves
  const int bnh=wn>>1, bc0=(wn&1)*64;     // B half + col-base within half
  f32x4 acc[8][4]={};

  // staging bases: load j in {0,1}: chunk c=j*8+wv -> kc=c>>1 (0..7), rh=c&1
  const u16* baseA[2]; const u16* baseB[2]; int dsto[2];
  #pragma unroll
  for(int j=0;j<2;++j){
    int c=j*8+wv, kc=c>>1, rh=c&1;
    baseA[j]=A + (r0 + rh*64 + ln)*DM + kc*8;
    baseB[j]=B + (size_t)(c0 + rh*64 + ln)*DM + kc*8;
    dsto[j]=kc*1024 + rh*512;            // wave-uniform LDS dest (u16); lane lands at +ln*8
  }
  auto STAGE_A=[&](int d,int kt,int h){
    #pragma unroll
    for(int j=0;j<2;++j)
      gload_lds16(baseA[j] + (size_t)h*128*DM + kt*64, smem + d*32768 + h*8192 + dsto[j]);
  };
  auto STAGE_B=[&](int d,int kt,int h){
    #pragma unroll
    for(int j=0;j<2;++j)
      gload_lds16(baseB[j] + (size_t)h*128*DM + kt*64, smem + d*32768 + 16384 + h*8192 + dsto[j]);
  };
  bf16x8 bq[4][2];
  auto LDB=[&](int d){
    #pragma unroll
    for(int n=0;n<4;++n)
      #pragma unroll
      for(int kk=0;kk<2;++kk)
        bq[n][kk]=*(const bf16x8*)(smem + d*32768 + 16384 + bnh*8192 + (kk*4+l4)*1024 + (bc0+n*16+l15)*8);
  };
  auto MM=[&](int d,int m0){
    bf16x8 af[2][2];
    #pragma unroll
    for(int mm=0;mm<2;++mm)
      #pragma unroll
      for(int kk=0;kk<2;++kk)
        af[mm][kk]=*(const bf16x8*)(smem + d*32768 + wm*8192 + (kk*4+l4)*1024 + ((m0+mm)*16+l15)*8);
    __builtin_amdgcn_s_barrier();
    asm volatile("s_waitcnt lgkmcnt(0)" ::: "memory");
    __builtin_amdgcn_sched_barrier(0);
    __builtin_amdgcn_s_setprio(1);
    #pragma unroll
    for(int mm=0;mm<2;++mm)
      #pragma unroll
      for(int kk=0;kk<2;++kk)
        #pragma unroll
        for(int n=0;n<4;++n)
          acc[m0+mm][n]=__builtin_amdgcn_mfma_f32_16x16x32_bf16(af[mm][kk],bq[n][kk],acc[m0+mm][n],0,0,0);
    __builtin_amdgcn_s_setprio(0);
  };
  auto ENDP=[&](){ __builtin_amdgcn_s_barrier(); __builtin_amdgcn_sched_barrier(0); };

  // prologue: K0 fully + K1.B (6 half-tiles, 12 loads/thread)
  STAGE_A(0,0,0); STAGE_A(0,0,1); STAGE_B(0,0,0); STAGE_B(0,0,1);
  STAGE_B(1,1,0); STAGE_B(1,1,1);
  asm volatile("s_waitcnt vmcnt(4)" ::: "memory");   // K0 landed (K1.B may be in flight)
  __builtin_amdgcn_s_barrier();
  __builtin_amdgcn_sched_barrier(0);

  #pragma clang loop unroll(disable)
  for(int i=0;i<4;++i){
    const bool st=(i<3);
    // ---- K-tile 2i (dbuf0), phases 0..3 ----
    LDB(0);
    STAGE_A(1,2*i+1,0); MM(0,0); ENDP();                       // ph0
    STAGE_A(1,2*i+1,1); MM(0,2); ENDP();                       // ph1
    if(st) STAGE_B(0,2*i+2,0); MM(0,4); ENDP();                // ph2
    if(st) STAGE_B(0,2*i+2,1); MM(0,6);                        // ph3
    if(st) asm volatile("s_waitcnt vmcnt(4)" ::: "memory");    //   dbuf1 K-tile ready
    else   asm volatile("s_waitcnt vmcnt(0)" ::: "memory");
    ENDP();
    // ---- K-tile 2i+1 (dbuf1), phases 4..7 ----
    LDB(1);
    if(st) STAGE_A(0,2*i+2,0); MM(1,0); ENDP();                // ph4
    if(st) STAGE_A(0,2*i+2,1); MM(1,2); ENDP();                // ph5
    if(st) STAGE_B(1,2*i+3,0); MM(1,4); ENDP();                // ph6
    if(st) STAGE_B(1,2*i+3,1); MM(1,6);                        // ph7
    if(st) asm volatile("s_waitcnt vmcnt(4)" ::: "memory");    //   dbuf0 next K-tile ready
    ENDP();
  }
  __syncthreads();

  // Epilogue: two half-restages (128 cols) through W[256][136] u16 (69.6 KB)
  // Store: each thread owns one (row, 64-col half): 8 x int4 = 64 u16 (full coverage).
  const bool isx=(c0<DI);
  const int cc0= isx? c0 : c0-DI;
  u16* W=smem;
  #pragma unroll
  for(int ch=0;ch<2;++ch){
    if((wn>>1)==ch){
      #pragma unroll
      for(int n=0;n<4;++n){
        int tcol=(wn&1)*64+n*16+l15;        // 0..127 within half
        int gcol=c0+ch*128+tcol;
        float cw = isx? convw[gcol*4+3]:0.f;
        float cb2= isx? convb[gcol]   :0.f;
        #pragma unroll
        for(int m=0;m<8;++m){
          int trow=wm*128+m*16+l4*4;
          #pragma unroll
          for(int r=0;r<4;++r){
            float v=acc[m][n][r];
            float o= isx? siluf(v*cw+cb2):siluf(v);
            W[(trow+r)*136+tcol]=f2bf(o);
          }
        }
      }
    }
    __syncthreads();
    const int row=tid>>1, half=tid&1;
    const u16* sp=W+row*136+half*64;
    u16* dst=(isx?xp:zs)+(r0+row)*DI+cc0+ch*128+half*64;
    #pragma unroll
    for(int j2=0;j2<8;++j2)
      ((int4*)dst)[j2]=((const int4*)sp)[j2];
    __syncthreads();
  }
}

// MERGED TAIL (R12-proven, unchanged): phase 1 = x_dbl GEMM -> dtb/bc in LDS;
// phase 2 = delta GEMM + w + y (LDS) + out GEMM vs wa + fcb.
__global__ __launch_bounds__(256) void k_tail(
  const u16* __restrict__ xp, const u16* __restrict__ xpw,
  const u16* __restrict__ dpw,
  const float* __restrict__ dpb, const float* __restrict__ Dv,
  const u16* __restrict__ zs, const u16* __restrict__ wa,
  const float* __restrict__ fcb, float* __restrict__ out)
{
  __shared__ u16 smem[29952];
  u16*   As  = smem;
  float* bcs = (float*)(smem + 4096);
  u16*   S   = smem + 4352;
  const int tid=threadIdx.x, wv=tid>>6, ln=tid&63;
  const int l15=ln&15, l4=ln>>4, h=l15&7;
  const int r0=blockIdx.x*128;
  const int wm=wv>>1, wn=wv&1;
  const int sr=ln>>3, scs=((ln&7)^sr)*8;
  const int chk0=(l4^h)*8, chk1=((l4+4)^h)*8;
  const int rA=(wm*64+l15)*64, rB=(wn*32+l15)*64;
  const int sr2=ln>>2, sc2=(ln&3)*8;

  {
    f32x4 acc[4][2]={};
    auto STAGE=[&](int buf, int k0){
      u16* Ad = S + buf*8192;
      u16* Bd = S + 16384 + buf*4096;
      #pragma unroll
      for (int it=0;it<4;++it){
        int c=wv*4+it;
        gload_lds16(xp + (size_t)(r0 + c*8 + sr)*DI + k0 + scs, Ad + c*512);
      }
      #pragma unroll
      for (int it=0;it<2;++it){
        int c=wv*2+it;
        gload_lds16(xpw + (size_t)(c*8 + sr)*DI + k0 + scs, Bd + c*512);
      }
    };
    STAGE(0, 0);
    __syncthreads();
    __builtin_amdgcn_sched_barrier(0);
    int cur = 0;
    #pragma clang loop unroll(disable)
    for (int t=0;t<16;++t){
      if (t < 15) STAGE(cur^1, (t+1)*64);
      const u16* Ac = S + cur*8192;
      const u16* Bc = S + 16384 + cur*4096;
      #pragma unroll
      for (int kk=0;kk<2;++kk){
        const int ch = kk ? chk1 : chk0;
        bf16x8 af[4], bfr[2];
        #pragma unroll
        for (int m=0;m<4;++m) af[m]=*(const bf16x8*)(Ac + rA + m*1024 + ch);
        #pragma unroll
        for (int n=0;n<2;++n) bfr[n]=*(const bf16x8*)(Bc + rB + n*1024 + ch);
        #pragma unroll
        for (int m=0;m<4;++m)
          #pragma unroll
          for (int n=0;n<2;++n)
            acc[m][n]=__builtin_amdgcn_mfma_f32_16x16x32_bf16(af[m],bfr[n],acc[m][n],0,0,0);
      }
      __syncthreads();
      __builtin_amdgcn_sched_barrier(0);
      cur ^= 1;
    }
    float* W = (float*)S;
    #pragma unroll
    for (int n=0;n<2;++n){
      int j = wn*32 + n*16 + l15;
      #pragma unroll
      for (int m=0;m<4;++m){
        int trow = wm*64 + m*16 + l4*4;
        #pragma unroll
        for (int r=0;r<4;++r)
          W[(trow+r)*68 + j] = acc[m][n][r];
      }
    }
    __syncthreads();
    const int row = tid>>1, half = tid&1;
    const float* wr = W + row*68;
    if (half==0){
      #pragma unroll
      for (int qv=0;qv<4;++qv){
        bf16x8 o;
        #pragma unroll
        for (int e=0;e<8;++e) o[e] = (short)f2bf(wr[qv*8+e]);
        *(bf16x8*)(As + row*32 + qv*8) = o;
      }
    } else {
      float s=0.f;
      #pragma unroll
      for (int e=0;e<16;++e) s += wr[32+e]*wr[48+e];
      bcs[row] = s;
    }
    {
      u16* Bs0 = S + 17408;
      #pragma unroll
      for (int it=0;it<2;++it){
        int c=wv*2+it;
        gload_lds16(dpw + (size_t)(c*16 + sr2)*32 + sc2, Bs0 + c*512);
      }
    }
    __syncthreads();
  }

  u16* Y   = S;
  u16* BsB = S + 17408;
  bf16x8 af[4];
  #pragma unroll
  for (int m=0;m<4;++m) af[m]=*(const bf16x8*)(As + (wm*64+m*16+l15)*32 + l4*8);

  f32x4 oacc[2][4]={};
  const int yrow = tid>>1, yhalf = tid&1;
  int cur = 0;

  #pragma clang loop unroll(disable)
  for (int ch=0; ch<8; ++ch){
    f32x4 dacc[4][4]={};
    bf16x8 bfr[4];
    #pragma unroll
    for (int n=0;n<4;++n) bfr[n]=*(const bf16x8*)(BsB + cur*4096 + (wn*64+n*16+l15)*32 + l4*8);
    #pragma unroll
    for (int m=0;m<4;++m)
      #pragma unroll
      for (int n=0;n<4;++n)
        dacc[m][n]=__builtin_amdgcn_mfma_f32_16x16x32_bf16(af[m],bfr[n],dacc[m][n],0,0,0);
    if (ch<7){
      #pragma unroll
      for (int it=0;it<2;++it){
        int c=wv*2+it;
        gload_lds16(dpw + (size_t)((ch+1)*128 + c*16 + sr2)*32 + sc2, BsB + (cur^1)*4096 + c*512);
      }
    }
    #pragma unroll
    for (int n=0;n<4;++n){
      int tcol = wn*64 + n*16 + l15;
      int j = ch*128 + tcol;
      float dpbj = dpb[j], Dj = Dv[j];
      #pragma unroll
      for (int m=0;m<4;++m){
        int trow = wm*64 + m*16 + l4*4;
        #pragma unroll
        for (int r=0;r<4;++r){
          float delta = softplus_fast(dacc[m][n][r] + dpbj);
          float w = delta*bcs[trow + r] + Dj;
          Y[(trow+r)*136 + tcol] = f2bf(w);
        }
      }
    }
    __syncthreads();
    {
      u16* wp = Y + yrow*136 + yhalf*64;
      const size_t gbase = (size_t)(r0 + yrow)*DI + ch*128 + yhalf*64;
      const u16* xpp = xp + gbase;
      const u16* zp  = zs + gbase;
      #pragma unroll
      for (int qq=0;qq<8;++qq){
        bf16x8 wv8 = *(const bf16x8*)(wp + qq*8);
        bf16x8 xv  = *(const bf16x8*)(xpp + qq*8);
        bf16x8 zv  = *(const bf16x8*)(zp + qq*8);
        bf16x8 ov;
        #pragma unroll
        for (int e=0;e<8;++e){
          float y = bf2f((u16)wv8[e]) * bf2f((u16)xv[e]) * bf2f((u16)zv[e]);
          ov[e] = (short)f2bf(y);
        }
        *(bf16x8*)(wp + qq*8) = ov;
      }
    }
    __syncthreads();
    #pragma unroll
    for (int kk=0;kk<4;++kk){
      bf16x8 af2[2], bf2r[4];
      #pragma unroll
      for (int m=0;m<2;++m)
        af2[m]=*(const bf16x8*)(Y + (wv*32 + m*16 + l15)*136 + kk*32 + l4*8);
      #pragma unroll
      for (int n=0;n<4;++n)
        bf2r[n]=*(const bf16x8*)(wa + (size_t)(n*16 + l15)*DI + ch*128 + kk*32 + l4*8);
      #pragma unroll
      for (int m=0;m<2;++m)
        #pragma unroll
        for (int n=0;n<4;++n)
          oacc[m][n]=__builtin_amdgcn_mfma_f32_16x16x32_bf16(af2[m],bf2r[n],oacc[m][n],0,0,0);
    }
    __syncthreads();
    __builtin_amdgcn_sched_barrier(0);
    cur ^= 1;
  }

  #pragma unroll
  for (int n=0;n<4;++n){
    int j = n*16 + l15;
    if (j < 36){
      float fj = fcb[j];
      #pragma unroll
      for (int m=0;m<2;++m){
        #pragma unroll
        for (int r=0;r<4;++r){
          int t = r0 + wv*32 + m*16 + l4*4 + r;
          out[(size_t)t*36 + j] = oacc[m][n][r] + fj;
        }
      }
    }
  }
}

extern "C" void kernel_launch(void* const* d_in, const int* in_sizes, int n_in,
                              void* d_out, int out_size, void* d_ws, size_t ws_size,
                              hipStream_t stream){
  const float* f      = (const float*)d_in[0];
  const float* inpw   = (const float*)d_in[1];
  const float* convw  = (const float*)d_in[2];
  const float* convb  = (const float*)d_in[3];
  const float* xprojw = (const float*)d_in[4];
  const float* dtpw   = (const float*)d_in[5];
  const float* dtpb   = (const float*)d_in[6];
  const float* Dv     = (const float*)d_in[8];
  const float* opw    = (const float*)d_in[9];
  const float* fcw    = (const float*)d_in[10];
  const float* fcb    = (const float*)d_in[11];
  float* out = (float*)d_out;

  char* ws = (char*)d_ws;
  size_t off = 0;
  auto alloc = [&](size_t sz)->void*{ void* p = ws + off; off += (sz + 255) & ~(size_t)255; return p; };
  u16*   fbf = (u16*)  alloc((size_t)NTOK*DM*2);
  u16*   xp  = (u16*)  alloc((size_t)NTOK*DI*2);
  u16*   zy  = (u16*)  alloc((size_t)NTOK*DI*2);
  u16*   ipw = (u16*)  alloc((size_t)2048*512*2);
  u16*   xpw = (u16*)  alloc((size_t)64*1024*2);
  u16*   dpw = (u16*)  alloc((size_t)1024*32*2);
  u16*   wa  = (u16*)  alloc((size_t)64*1024*2);
  if (off > ws_size){ k_sentinel<<<1,1,0,stream>>>(out); return; }

  k_cast_bf16<<<dim3((NTOK*DM/4)/256),256,0,stream>>>(f, fbf, NTOK*DM);
  k_cast_weights<<<dim3(1120),256,0,stream>>>(inpw, xprojw, dtpw, ipw, xpw, dpw);
  k_make_wa<<<dim3(4,64),256,0,stream>>>(fcw, opw, wa);

  k_gemm_xz<<<dim3(2048),512,0,stream>>>(fbf, ipw, convw, convb, xp, zy);
  k_tail<<<dim3(512),256,0,stream>>>(xp, xpw, dpw, dtpb, Dv, zy, wa, fcb, out);
}

// Round 16
// 465.825 us; speedup vs baseline: 1.2520x; 1.2043x over previous
//
#include <hip/hip_runtime.h>

typedef unsigned short u16;
typedef unsigned int u32;
typedef __attribute__((ext_vector_type(8))) short bf16x8;
typedef __attribute__((ext_vector_type(4))) float f32x4;

#define NTOK 65536
#define DM 512
#define DI 1024

__device__ __forceinline__ float bf2f(u16 u){ u32 x=((u32)u)<<16; float f; __builtin_memcpy(&f,&x,4); return f; }
__device__ __forceinline__ u16 f2bf(float f){ u32 u; __builtin_memcpy(&u,&f,4); u += 0x7fffu + ((u>>16)&1u); return (u16)(u>>16); }
__device__ __forceinline__ float siluf(float x){ return x/(1.f+__expf(-x)); }
// fast softplus: log(1+e^x) via HW exp/log; guard matches reference large-x behavior
__device__ __forceinline__ float softplus_fast(float x){
  float l = __logf(1.f + __expf(x));
  return (x > 20.f) ? x : l;
}

__device__ __forceinline__ void gload_lds16(const void* g, void* l){
  __builtin_amdgcn_global_load_lds((const __attribute__((address_space(1))) u32*)g,
                                   (__attribute__((address_space(3))) u32*)l, 16, 0, 0);
}

__global__ void k_sentinel(float* out){ out[0] = 1.2345e6f; }

__global__ void k_cast_bf16(const float* __restrict__ in, u16* __restrict__ out, int n){
  int i = (blockIdx.x*256 + threadIdx.x)*4;
  if (i >= n) return;
  float4 v = *(const float4*)(in + i);
  ushort4 o; o.x=f2bf(v.x); o.y=f2bf(v.y); o.z=f2bf(v.z); o.w=f2bf(v.w);
  *(ushort4*)(out + i) = o;
}

// one launch for the three small weight casts: ipw (1M), xpw (64K), dpw (32K)
__global__ void k_cast_weights(const float* __restrict__ ipw_f, const float* __restrict__ xpw_f,
                               const float* __restrict__ dpw_f,
                               u16* __restrict__ ipw, u16* __restrict__ xpw, u16* __restrict__ dpw){
  int b = blockIdx.x;
  const float* src; u16* dst; int base;
  if (b < 1024){ src=ipw_f; dst=ipw; base = b*1024; }
  else if (b < 1088){ src=xpw_f; dst=xpw; base = (b-1024)*1024; }
  else { src=dpw_f; dst=dpw; base = (b-1088)*1024; }
  int i = base + threadIdx.x*4;
  float4 v = *(const float4*)(src + i);
  ushort4 o; o.x=f2bf(v.x); o.y=f2bf(v.y); o.z=f2bf(v.z); o.w=f2bf(v.w);
  *(ushort4*)(dst + i) = o;
}

// W_a[i][j] = sum_c fc_w[i][c] * out_proj_w[c][j], padded to 64 rows (zeros), bf16
__global__ void k_make_wa(const float* __restrict__ fcw, const float* __restrict__ opw,
                          u16* __restrict__ wa){
  int j = blockIdx.x*256 + threadIdx.x;   // 0..1023
  int i = blockIdx.y;                     // 0..63
  float s = 0.f;
  if (i < 36){
    const float* fr = fcw + i*DM;
    #pragma unroll 8
    for (int k=0;k<DM;++k) s += fr[k]*opw[(size_t)k*DI + j];
  }
  wa[(size_t)i*DI + j] = f2bf(s);
}

// xz = f @ in_proj^T ; dbuf + swizzled LDS + LDS-restaged coalesced epilogue.
// R4 kernel + XCD-bijective remap (R11-proven). grid (16,512).
__global__ __launch_bounds__(256) void k_gemm_xz(
  const u16* __restrict__ A, const u16* __restrict__ B,
  const float* __restrict__ convw, const float* __restrict__ convb,
  u16* __restrict__ xp, u16* __restrict__ zs)
{
  __shared__ u16 smem[32768];             // 64 KB: As0|As1|Bs0|Bs1 (8192 u16 each)
  u16* SA = smem;                         // +buf*8192
  u16* SB = smem + 16384;                 // +buf*8192
  const int tid=threadIdx.x, wv=tid>>6, ln=tid&63;
  const int l15=ln&15, l4=ln>>4, h=l15&7;
  const int l = blockIdx.y*16 + blockIdx.x;
  const int xcd = l & 7, q = l >> 3;
  const int cb = q & 15;                  // col-block 0..15
  const int g  = (q >> 4)*8 + xcd;        // row-group 0..511 (bijective)
  const int c0g = cb*128, r0 = g*128;
  const int wm=wv>>1, wn=wv&1;
  const int sr=ln>>3, scs=((ln&7)^sr)*8;       // pre-swizzled global col chunk
  const int chk0=(l4^h)*8, chk1=((l4+4)^h)*8;  // swizzled read chunk offsets (u16)
  const int rA=(wm*64+l15)*64, rB=(wn*64+l15)*64;
  f32x4 acc[4][4]={};

  auto STAGE=[&](int buf, int k0){
    u16* Ad = SA + buf*8192;
    u16* Bd = SB + buf*8192;
    #pragma unroll
    for (int it=0;it<4;++it){
      int c=wv*4+it;
      gload_lds16(A + (size_t)(r0 + c*8 + sr)*DM + k0 + scs, Ad + c*512);
    }
    #pragma unroll
    for (int it=0;it<4;++it){
      int c=wv*4+it;
      gload_lds16(B + (size_t)(c0g + c*8 + sr)*DM + k0 + scs, Bd + c*512);
    }
  };

  STAGE(0, 0);
  __syncthreads();
  __builtin_amdgcn_sched_barrier(0);
  int cur = 0;
  #pragma clang loop unroll(disable)
  for (int t=0;t<8;++t){
    if (t < 7) STAGE(cur^1, (t+1)*64);
    const u16* Ac = SA + cur*8192;
    const u16* Bc = SB + cur*8192;
    #pragma unroll
    for (int kk=0;kk<2;++kk){
      const int ch = kk ? chk1 : chk0;
      bf16x8 af[4], bfr[4];
      #pragma unroll
      for (int m=0;m<4;++m) af[m]=*(const bf16x8*)(Ac + rA + m*1024 + ch);
      #pragma unroll
      for (int n=0;n<4;++n) bfr[n]=*(const bf16x8*)(Bc + rB + n*1024 + ch);
      #pragma unroll
      for (int m=0;m<4;++m)
        #pragma unroll
        for (int n=0;n<4;++n)
          acc[m][n]=__builtin_amdgcn_mfma_f32_16x16x32_bf16(af[m],bfr[n],acc[m][n],0,0,0);
    }
    __syncthreads();
    __builtin_amdgcn_sched_barrier(0);
    cur ^= 1;
  }

  // Epilogue: activation -> LDS tile [128][160 u16] (320B stride) -> coalesced stores
  const bool isx = (c0g < DI);
  const int cc0 = isx ? c0g : c0g - DI;
  u16* ep = smem;
  #pragma unroll
  for (int n=0;n<4;++n){
    int tcol = wn*64 + n*16 + l15;
    int gcol = c0g + tcol;
    float cw = isx ? convw[gcol*4+3] : 0.f;
    float cb2= isx ? convb[gcol]     : 0.f;
    #pragma unroll
    for (int m=0;m<4;++m){
      int trow = wm*64 + m*16 + l4*4;
      #pragma unroll
      for (int r=0;r<4;++r){
        float v = acc[m][n][r];
        float o = isx ? siluf(v*cw + cb2) : siluf(v);
        ep[(trow+r)*160 + tcol] = f2bf(o);
      }
    }
  }
  __syncthreads();
  int rrow = tid>>1, half = tid&1;
  const u16* srcp = ep + rrow*160 + half*64;
  u16* dst = (isx ? xp : zs) + (size_t)(r0+rrow)*DI + cc0 + half*64;
  #pragma unroll
  for (int j=0;j<8;++j)
    *(int4*)(dst + j*8) = *(const int4*)(srcp + j*8);
}

// MERGED TAIL: phase 1 = x_dbl GEMM (xp @ xpw^T, K=1024) -> dtb/bc in LDS;
// phase 2 = delta GEMM + w=softplus*bc+D + y=w*xp*zs (LDS) + out GEMM vs wa + fcb.
// grid 512 x 256 thr (4 waves). 59.9 KB LDS -> 2 blocks/CU. All plain __syncthreads.
__global__ __launch_bounds__(256) void k_tail(
  const u16* __restrict__ xp, const u16* __restrict__ xpw,
  const u16* __restrict__ dpw,
  const float* __restrict__ dpb, const float* __restrict__ Dv,
  const u16* __restrict__ zs, const u16* __restrict__ wa,
  const float* __restrict__ fcb, float* __restrict__ out)
{
  __shared__ u16 smem[29952];            // 59.9 KB
  u16*   As  = smem;                     // [0,4096): dt tile 128x32 bf16 (persistent)
  float* bcs = (float*)(smem + 4096);    // [4096,4352): bc[128] (persistent)
  u16*   S   = smem + 4352;              // 25600 u16 scratch
  const int tid=threadIdx.x, wv=tid>>6, ln=tid&63;
  const int l15=ln&15, l4=ln>>4, h=l15&7;
  const int r0=blockIdx.x*128;
  const int wm=wv>>1, wn=wv&1;
  const int sr=ln>>3, scs=((ln&7)^sr)*8;
  const int chk0=(l4^h)*8, chk1=((l4+4)^h)*8;
  const int rA=(wm*64+l15)*64, rB=(wn*32+l15)*64;
  const int sr2=ln>>2, sc2=(ln&3)*8;     // phase-2 staging map (16 rows/chunk)

  // ---------------- phase 1: x_dbl = xp @ xpw^T ----------------
  {
    f32x4 acc[4][2]={};
    auto STAGE=[&](int buf, int k0){
      u16* Ad = S + buf*8192;
      u16* Bd = S + 16384 + buf*4096;
      #pragma unroll
      for (int it=0;it<4;++it){
        int c=wv*4+it;
        gload_lds16(xp + (size_t)(r0 + c*8 + sr)*DI + k0 + scs, Ad + c*512);
      }
      #pragma unroll
      for (int it=0;it<2;++it){
        int c=wv*2+it;
        gload_lds16(xpw + (size_t)(c*8 + sr)*DI + k0 + scs, Bd + c*512);
      }
    };
    STAGE(0, 0);
    __syncthreads();
    __builtin_amdgcn_sched_barrier(0);
    int cur = 0;
    #pragma clang loop unroll(disable)
    for (int t=0;t<16;++t){
      if (t < 15) STAGE(cur^1, (t+1)*64);
      const u16* Ac = S + cur*8192;
      const u16* Bc = S + 16384 + cur*4096;
      #pragma unroll
      for (int kk=0;kk<2;++kk){
        const int ch = kk ? chk1 : chk0;
        bf16x8 af[4], bfr[2];
        #pragma unroll
        for (int m=0;m<4;++m) af[m]=*(const bf16x8*)(Ac + rA + m*1024 + ch);
        #pragma unroll
        for (int n=0;n<2;++n) bfr[n]=*(const bf16x8*)(Bc + rB + n*1024 + ch);
        #pragma unroll
        for (int m=0;m<4;++m)
          #pragma unroll
          for (int n=0;n<2;++n)
            acc[m][n]=__builtin_amdgcn_mfma_f32_16x16x32_bf16(af[m],bfr[n],acc[m][n],0,0,0);
      }
      __syncthreads();
      __builtin_amdgcn_sched_barrier(0);
      cur ^= 1;
    }
    // restage fp32 x_dbl tile [128][68] over dead SA/SB
    float* W = (float*)S;
    #pragma unroll
    for (int n=0;n<2;++n){
      int j = wn*32 + n*16 + l15;
      #pragma unroll
      for (int m=0;m<4;++m){
        int trow = wm*64 + m*16 + l4*4;
        #pragma unroll
        for (int r=0;r<4;++r)
          W[(trow+r)*68 + j] = acc[m][n][r];
      }
    }
    __syncthreads();
    // emit As (bf16 dt tile) + bcs; stage Bs[0] (disjoint region S+17408..) in parallel
    const int row = tid>>1, half = tid&1;
    const float* wr = W + row*68;
    if (half==0){
      #pragma unroll
      for (int qv=0;qv<4;++qv){
        bf16x8 o;
        #pragma unroll
        for (int e=0;e<8;++e) o[e] = (short)f2bf(wr[qv*8+e]);
        *(bf16x8*)(As + row*32 + qv*8) = o;
      }
    } else {
      float s=0.f;
      #pragma unroll
      for (int e=0;e<16;++e) s += wr[32+e]*wr[48+e];
      bcs[row] = s;
    }
    {
      u16* Bs0 = S + 17408;
      #pragma unroll
      for (int it=0;it<2;++it){
        int c=wv*2+it;
        gload_lds16(dpw + (size_t)(c*16 + sr2)*32 + sc2, Bs0 + c*512);
      }
    }
    __syncthreads();   // drains gload (vmcnt) + orders As/bcs/W
  }

  // ---------------- phase 2: delta + y + out GEMM ----------------
  u16* Y   = S;                  // overwrites dead W
  u16* BsB = S + 17408;          // 2 x 4096 u16
  bf16x8 af[4];                  // persistent dt A-frags
  #pragma unroll
  for (int m=0;m<4;++m) af[m]=*(const bf16x8*)(As + (wm*64+m*16+l15)*32 + l4*8);

  f32x4 oacc[2][4]={};
  const int yrow = tid>>1, yhalf = tid&1;
  int cur = 0;

  #pragma clang loop unroll(disable)
  for (int ch=0; ch<8; ++ch){
    // GEMM1: delta chunk (128 x 128), K=32
    f32x4 dacc[4][4]={};
    bf16x8 bfr[4];
    #pragma unroll
    for (int n=0;n<4;++n) bfr[n]=*(const bf16x8*)(BsB + cur*4096 + (wn*64+n*16+l15)*32 + l4*8);
    #pragma unroll
    for (int m=0;m<4;++m)
      #pragma unroll
      for (int n=0;n<4;++n)
        dacc[m][n]=__builtin_amdgcn_mfma_f32_16x16x32_bf16(af[m],bfr[n],dacc[m][n],0,0,0);
    if (ch<7){
      #pragma unroll
      for (int it=0;it<2;++it){
        int c=wv*2+it;
        gload_lds16(dpw + (size_t)((ch+1)*128 + c*16 + sr2)*32 + sc2, BsB + (cur^1)*4096 + c*512);
      }
    }
    // w-pass: w = softplus(dacc+dpb)*bc+D -> Y (bf16, frag-scatter)
    #pragma unroll
    for (int n=0;n<4;++n){
      int tcol = wn*64 + n*16 + l15;           // 0..127
      int j = ch*128 + tcol;
      float dpbj = dpb[j], Dj = Dv[j];
      #pragma unroll
      for (int m=0;m<4;++m){
        int trow = wm*64 + m*16 + l4*4;
        #pragma unroll
        for (int r=0;r<4;++r){
          float delta = softplus_fast(dacc[m][n][r] + dpbj);
          float w = delta*bcs[trow + r] + Dj;
          Y[(trow+r)*136 + tcol] = f2bf(w);
        }
      }
    }
    __syncthreads();
    // y-finish: y = w * xp * zs, vectorized, back into Y
    {
      u16* wp = Y + yrow*136 + yhalf*64;
      const size_t gbase = (size_t)(r0 + yrow)*DI + ch*128 + yhalf*64;
      const u16* xpp = xp + gbase;
      const u16* zp  = zs + gbase;
      #pragma unroll
      for (int qq=0;qq<8;++qq){
        bf16x8 wv8 = *(const bf16x8*)(wp + qq*8);
        bf16x8 xv  = *(const bf16x8*)(xpp + qq*8);
        bf16x8 zv  = *(const bf16x8*)(zp + qq*8);
        bf16x8 ov;
        #pragma unroll
        for (int e=0;e<8;++e){
          float y = bf2f((u16)wv8[e]) * bf2f((u16)xv[e]) * bf2f((u16)zv[e]);
          ov[e] = (short)f2bf(y);
        }
        *(bf16x8*)(wp + qq*8) = ov;
      }
    }
    __syncthreads();
    // GEMM2: out += y_chunk (128x128) @ wa_chunk^T (64x128)
    #pragma unroll
    for (int kk=0;kk<4;++kk){
      bf16x8 af2[2], bf2r[4];
      #pragma unroll
      for (int m=0;m<2;++m)
        af2[m]=*(const bf16x8*)(Y + (wv*32 + m*16 + l15)*136 + kk*32 + l4*8);
      #pragma unroll
      for (int n=0;n<4;++n)
        bf2r[n]=*(const bf16x8*)(wa + (size_t)(n*16 + l15)*DI + ch*128 + kk*32 + l4*8);
      #pragma unroll
      for (int m=0;m<2;++m)
        #pragma unroll
        for (int n=0;n<4;++n)
          oacc[m][n]=__builtin_amdgcn_mfma_f32_16x16x32_bf16(af2[m],bf2r[n],oacc[m][n],0,0,0);
    }
    __syncthreads();   // Y reads done before next w-pass; Bs prefetch landed
    __builtin_amdgcn_sched_barrier(0);
    cur ^= 1;
  }

  // epilogue: out[t*36+j] = oacc + fcb[j], j<36
  #pragma unroll
  for (int n=0;n<4;++n){
    int j = n*16 + l15;
    if (j < 36){
      float fj = fcb[j];
      #pragma unroll
      for (int m=0;m<2;++m){
        #pragma unroll
        for (int r=0;r<4;++r){
          int t = r0 + wv*32 + m*16 + l4*4 + r;
          out[(size_t)t*36 + j] = oacc[m][n][r] + fj;
        }
      }
    }
  }
}

extern "C" void kernel_launch(void* const* d_in, const int* in_sizes, int n_in,
                              void* d_out, int out_size, void* d_ws, size_t ws_size,
                              hipStream_t stream){
  const float* f      = (const float*)d_in[0];
  const float* inpw   = (const float*)d_in[1];
  const float* convw  = (const float*)d_in[2];
  const float* convb  = (const float*)d_in[3];
  const float* xprojw = (const float*)d_in[4];
  const float* dtpw   = (const float*)d_in[5];
  const float* dtpb   = (const float*)d_in[6];
  const float* Dv     = (const float*)d_in[8];
  const float* opw    = (const float*)d_in[9];
  const float* fcw    = (const float*)d_in[10];
  const float* fcb    = (const float*)d_in[11];
  float* out = (float*)d_out;

  char* ws = (char*)d_ws;
  size_t off = 0;
  auto alloc = [&](size_t sz)->void*{ void* p = ws + off; off += (sz + 255) & ~(size_t)255; return p; };
  u16*   fbf = (u16*)  alloc((size_t)NTOK*DM*2);
  u16*   xp  = (u16*)  alloc((size_t)NTOK*DI*2);
  u16*   zy  = (u16*)  alloc((size_t)NTOK*DI*2);
  u16*   ipw = (u16*)  alloc((size_t)2048*512*2);
  u16*   xpw = (u16*)  alloc((size_t)64*1024*2);
  u16*   dpw = (u16*)  alloc((size_t)1024*32*2);
  u16*   wa  = (u16*)  alloc((size_t)64*1024*2);
  if (off > ws_size){ k_sentinel<<<1,1,0,stream>>>(out); return; }

  k_cast_bf16<<<dim3((NTOK*DM/4)/256),256,0,stream>>>(f, fbf, NTOK*DM);
  k_cast_weights<<<dim3(1120),256,0,stream>>>(inpw, xprojw, dtpw, ipw, xpw, dpw);
  k_make_wa<<<dim3(4,64),256,0,stream>>>(fcw, opw, wa);

  k_gemm_xz<<<dim3(16,512),256,0,stream>>>(fbf, ipw, convw, convb, xp, zy);
  k_tail<<<dim3(512),256,0,stream>>>(xp, xpw, dpw, dtpb, Dv, zy, wa, fcb, out);
}